// Round 8
// baseline (367.966 us; speedup 1.0000x reference)
//
#include <hip/hip_runtime.h>
#include <stdint.h>

#define B_ 4
#define L_ 2048
#define H_ 8
#define E_ 64
#define S_ 2048

typedef __bf16 bf16x8 __attribute__((ext_vector_type(8)));
typedef _Float16 f16x8 __attribute__((ext_vector_type(8)));
typedef _Float16 f16x2 __attribute__((ext_vector_type(2)));
typedef float f32x4 __attribute__((ext_vector_type(4)));
typedef unsigned short u16;
typedef u16 u16x4 __attribute__((ext_vector_type(4)));
typedef uint32_t u32;

__device__ __forceinline__ u16 f32_to_bf16(float f) {
  union { float f; uint32_t u; } x;
  x.f = f;
  uint32_t u = x.u;
  return (u16)((u + 0x7FFFu + ((u >> 16) & 1u)) >> 16);
}

// q' = bf16(q * tau[b]/sqrt(E) * log2e), k' = bf16(k), delta' = delta/sqrt(E)*log2e
__global__ __launch_bounds__(256) void prep_qkd(
    const float* __restrict__ q, const float* __restrict__ k,
    const float* __restrict__ tau, const float* __restrict__ delta,
    u16* __restrict__ qb, u16* __restrict__ kb, float* __restrict__ dl) {
  int idx = blockIdx.x * 256 + threadIdx.x;  // 0 .. 1048575
  int i4 = idx * 4;
  int b = i4 >> 20;
  const float C = 0.125f * 1.44269504088896f;
  float ts = tau[b] * C;
  f32x4 qv = *(const f32x4*)(q + i4);
  f32x4 kv = *(const f32x4*)(k + i4);
  u16x4 qs, ks;
#pragma unroll
  for (int j = 0; j < 4; ++j) {
    qs[j] = f32_to_bf16(qv[j] * ts);
    ks[j] = f32_to_bf16(kv[j]);
  }
  *(u16x4*)(qb + i4) = qs;
  *(u16x4*)(kb + i4) = ks;
  if (idx < (B_ * S_) / 4) {
    f32x4 dv = *(const f32x4*)(delta + i4);
    f32x4 ds = {dv[0] * C, dv[1] * C, dv[2] * C, dv[3] * C};
    *(f32x4*)(dl + i4) = ds;
  }
}

// V [B,S,H,E] f32 -> V' [B,H,E,S] fp16 (tiled transpose)
__global__ __launch_bounds__(256) void prep_v(const float* __restrict__ v,
                                              u16* __restrict__ vb) {
  __shared__ float t[32][33];
  int bid = blockIdx.x;
  int et = bid & 1;
  int st = (bid >> 1) & 63;
  int h = (bid >> 7) & 7;
  int b = bid >> 10;
  int tx = threadIdx.x & 31;
  int ty = threadIdx.x >> 5;
#pragma unroll
  for (int k2 = 0; k2 < 4; ++k2) {
    int s = st * 32 + ty + 8 * k2;
    int e = et * 32 + tx;
    t[ty + 8 * k2][tx] = v[(((size_t)b * S_ + s) * H_ + h) * E_ + e];
  }
  __syncthreads();
#pragma unroll
  for (int k2 = 0; k2 < 4; ++k2) {
    int e = et * 32 + ty + 8 * k2;
    int s = st * 32 + tx;
    _Float16 hf = (_Float16)t[tx][ty + 8 * k2];
    vb[(((size_t)b * H_ + h) * E_ + e) * S_ + s] = __builtin_bit_cast(u16, hf);
  }
}

// Tile = 64 q-rows of one (b,h); 2 waves per tile (s-halves); 2 tiles per WG.
// Sweep 1: swapped QK^T -> exp (regs only) -> inline sums + PV (shuffle-dance frags).
// Sweep 2: recompute QK^T (L2-hot K) -> a = exp2 * zinv, full-line f32x4 stores.
__global__ __launch_bounds__(256, 2) void attn_fused(
    const u16* __restrict__ qb, const u16* __restrict__ kb,
    const u16* __restrict__ vbuf, const float* __restrict__ dl,
    float* __restrict__ out, float* __restrict__ oa) {
  __shared__ float sums_x[2][2][4][16];  // [half][tile][g][q16]
  __shared__ float out_x[2][64][65];     // [tile][row][e] (pad 65)

  int bid = blockIdx.x;
  int swz = (bid & 7) * 64 + (bid >> 3);  // 512 WGs, 8 XCDs
  int tid = threadIdx.x, lane = tid & 63, wid = tid >> 6;
  int tl = wid >> 1;           // tile slot in WG
  int half = wid & 1;          // s-half
  int tgl = swz * 2 + tl;      // global tile 0..1023
  int pane = tgl >> 5;         // (b,h)
  int b = pane >> 3, h = pane & 7;
  int m0 = (tgl & 31) * 64;
  int l15 = lane & 15, l4 = lane >> 4;
  int s0 = half * 1024;

  // Q frags (B operand): col q = l15 (+16g), k(e) = 8*l4 + j
  bf16x8 qa[4][2];
#pragma unroll
  for (int g = 0; g < 4; ++g) {
    const u16* qp =
        qb + (((size_t)b * L_ + (m0 + 16 * g + l15)) * H_ + h) * E_ + 8 * l4;
    qa[g][0] = *(const bf16x8*)qp;
    qa[g][1] = *(const bf16x8*)(qp + 32);
  }

  const u16* kbase = kb + (((size_t)b * S_ + (s0 + l15)) * H_ + h) * E_ + 8 * l4;
  const float* dbase = dl + b * S_ + s0 + 4 * l4;
  const u16* vrow = vbuf + ((size_t)pane * E_ + l15) * S_ + s0 + 8 * l4;

  // ---- Sweep 1: sums + PV ----
  float sums[4] = {0.f, 0.f, 0.f, 0.f};
  f32x4 oacc[4][4];
#pragma unroll
  for (int g = 0; g < 4; ++g)
#pragma unroll
    for (int et = 0; et < 4; ++et) oacc[g][et] = (f32x4){0.f, 0.f, 0.f, 0.f};

  int gsel = l4 >> 1;
  int src0 = l15 + 16 * ((l4 & 1) * 2);
  int src1 = src0 + 16;

#pragma unroll 1
  for (int c = 0; c < 32; ++c) {  // 32-s chunks (t = 2c, 2c+1)
    u32 pp[4][4];
#pragma unroll
    for (int tt = 0; tt < 2; ++tt) {
      int t = 2 * c + tt;
      const u16* kp = kbase + (size_t)t * (16 * H_ * E_);
      bf16x8 ka0 = *(const bf16x8*)kp;
      bf16x8 ka1 = *(const bf16x8*)(kp + 32);
      f32x4 dv = *(const f32x4*)(dbase + 16 * t);
#pragma unroll
      for (int g = 0; g < 4; ++g) {
        f32x4 acc = {0.f, 0.f, 0.f, 0.f};
        acc = __builtin_amdgcn_mfma_f32_16x16x32_bf16(ka0, qa[g][0], acc, 0, 0, 0);
        acc = __builtin_amdgcn_mfma_f32_16x16x32_bf16(ka1, qa[g][1], acc, 0, 0, 0);
        float p0 = __builtin_amdgcn_exp2f(acc[0] + dv[0]);
        float p1 = __builtin_amdgcn_exp2f(acc[1] + dv[1]);
        float p2 = __builtin_amdgcn_exp2f(acc[2] + dv[2]);
        float p3 = __builtin_amdgcn_exp2f(acc[3] + dv[3]);
        sums[g] += (p0 + p1) + (p2 + p3);
        pp[g][2 * tt] = __builtin_bit_cast(u32, (f16x2){(_Float16)p0, (_Float16)p1});
        pp[g][2 * tt + 1] = __builtin_bit_cast(u32, (f16x2){(_Float16)p2, (_Float16)p3});
      }
    }
    // shuffle-dance: build PV A-frags (row q=l15, k = s-local 8*l4+j) per group
    f16x8 af[4];
#pragma unroll
    for (int g = 0; g < 4; ++g) {
      union { u32 w[4]; f16x8 v; } u;
      u32 a0 = (u32)__shfl((int)pp[g][0], src0, 64);
      u32 b0 = (u32)__shfl((int)pp[g][2], src0, 64);
      u.w[0] = gsel ? b0 : a0;
      u32 a1 = (u32)__shfl((int)pp[g][1], src0, 64);
      u32 b1 = (u32)__shfl((int)pp[g][3], src0, 64);
      u.w[1] = gsel ? b1 : a1;
      u32 a2 = (u32)__shfl((int)pp[g][0], src1, 64);
      u32 b2 = (u32)__shfl((int)pp[g][2], src1, 64);
      u.w[2] = gsel ? b2 : a2;
      u32 a3 = (u32)__shfl((int)pp[g][1], src1, 64);
      u32 b3 = (u32)__shfl((int)pp[g][3], src1, 64);
      u.w[3] = gsel ? b3 : a3;
      af[g] = u.v;
    }
#pragma unroll
    for (int et = 0; et < 4; ++et) {
      f16x8 vf = *(const f16x8*)(vrow + (size_t)et * 16 * S_ + 32 * c);
#pragma unroll
      for (int g = 0; g < 4; ++g)
        oacc[g][et] = __builtin_amdgcn_mfma_f32_16x16x32_f16(af[g], vf, oacc[g][et], 0, 0, 0);
    }
  }
#pragma unroll
  for (int g = 0; g < 4; ++g) {
    sums[g] += __shfl_xor(sums[g], 16, 64);
    sums[g] += __shfl_xor(sums[g], 32, 64);
  }
  if (lane < 16) {
#pragma unroll
    for (int g = 0; g < 4; ++g) sums_x[half][tl][g][lane] = sums[g];
  }
  __syncthreads();
  float zinv[4];
#pragma unroll
  for (int g = 0; g < 4; ++g)
    zinv[g] = 1.f / (sums_x[0][tl][g][l15] + sums_x[1][tl][g][l15]);

  // ---- Sweep 2: recompute + normalized a stores (loads rotated ahead of stores) ----
  float* abase = oa + ((size_t)pane * L_ + m0) * S_ + s0;
  {
    bf16x8 ka0c = *(const bf16x8*)kbase;
    bf16x8 ka1c = *(const bf16x8*)(kbase + 32);
    f32x4 dvc = *(const f32x4*)dbase;
#pragma unroll 1
    for (int t = 0; t < 64; ++t) {
      bf16x8 ka0n, ka1n;
      f32x4 dvn;
      if (t < 63) {
        const u16* kp = kbase + (size_t)(t + 1) * (16 * H_ * E_);
        ka0n = *(const bf16x8*)kp;
        ka1n = *(const bf16x8*)(kp + 32);
        dvn = *(const f32x4*)(dbase + 16 * (t + 1));
      }
#pragma unroll
      for (int g = 0; g < 4; ++g) {
        f32x4 acc = {0.f, 0.f, 0.f, 0.f};
        acc = __builtin_amdgcn_mfma_f32_16x16x32_bf16(ka0c, qa[g][0], acc, 0, 0, 0);
        acc = __builtin_amdgcn_mfma_f32_16x16x32_bf16(ka1c, qa[g][1], acc, 0, 0, 0);
        f32x4 av = {__builtin_amdgcn_exp2f(acc[0] + dvc[0]) * zinv[g],
                    __builtin_amdgcn_exp2f(acc[1] + dvc[1]) * zinv[g],
                    __builtin_amdgcn_exp2f(acc[2] + dvc[2]) * zinv[g],
                    __builtin_amdgcn_exp2f(acc[3] + dvc[3]) * zinv[g]};
        *(f32x4*)(abase + (size_t)(16 * g + l15) * S_ + 16 * t + 4 * l4) = av;
      }
      ka0c = ka0n;
      ka1c = ka1n;
      dvc = dvn;
    }
  }

  // ---- out: half 1 parks partials in LDS; half 0 combines and stores ----
  if (half == 1) {
#pragma unroll
    for (int g = 0; g < 4; ++g)
#pragma unroll
      for (int et = 0; et < 4; ++et)
#pragma unroll
        for (int r = 0; r < 4; ++r)
          out_x[tl][16 * g + 4 * l4 + r][16 * et + l15] = oacc[g][et][r];
  }
  __syncthreads();
  if (half == 0) {
#pragma unroll
    for (int g = 0; g < 4; ++g)
#pragma unroll
      for (int r = 0; r < 4; ++r) {
        int row = 16 * g + 4 * l4 + r;
        float zr = 1.f / (sums_x[0][tl][g][4 * l4 + r] + sums_x[1][tl][g][4 * l4 + r]);
#pragma unroll
        for (int et = 0; et < 4; ++et)
          out[(((size_t)b * L_ + (m0 + row)) * H_ + h) * E_ + 16 * et + l15] =
              (oacc[g][et][r] + out_x[tl][row][16 * et + l15]) * zr;
      }
  }
}

extern "C" void kernel_launch(void* const* d_in, const int* in_sizes, int n_in,
                              void* d_out, int out_size, void* d_ws, size_t ws_size,
                              hipStream_t stream) {
  (void)in_sizes; (void)n_in; (void)out_size;
  const float* q = (const float*)d_in[0];
  const float* k = (const float*)d_in[1];
  const float* v = (const float*)d_in[2];
  const float* tau = (const float*)d_in[3];
  const float* delta = (const float*)d_in[4];
  float* out = (float*)d_out;
  float* oa = out + (size_t)B_ * L_ * H_ * E_;

  const size_t NQ = (size_t)B_ * L_ * H_ * E_;  // 4194304
  u16* qb = (u16*)d_ws;
  u16* kb = qb + NQ;
  u16* vb = kb + NQ;
  float* dl = (float*)(vb + NQ);
  size_t need = 3 * NQ * sizeof(u16) + (size_t)B_ * S_ * sizeof(float);
  if (ws_size < need) return;

  prep_qkd<<<4096, 256, 0, stream>>>(q, k, tau, delta, qb, kb, dl);
  prep_v<<<4096, 256, 0, stream>>>(v, vb);
  attn_fused<<<512, 256, 0, stream>>>(qb, kb, vb, dl, out, oa);
}